// Round 15
// baseline (9525.359 us; speedup 1.0000x reference)
//
#include <hip/hip_runtime.h>
#include <hip/hip_cooperative_groups.h>

static constexpr int BB  = 4;
static constexpr int SS  = 512;
static constexpr int DD  = 1024;
static constexpr int HH  = 16;
static constexpr int LL  = 4;
static constexpr int VV  = 32000;
static constexpr int DHH = 64;
static constexpr int FFF = 4096;

typedef short bf16x8  __attribute__((ext_vector_type(8)));
typedef short bf16x4v __attribute__((ext_vector_type(4)));
typedef float f32x4   __attribute__((ext_vector_type(4)));

__device__ __forceinline__ float b2f(ushort u){
  union { float f; unsigned int u32; } x; x.u32 = ((unsigned int)u) << 16; return x.f;
}
__device__ __forceinline__ ushort f2b(float f){
  union { float f; unsigned int u32; } x; x.f = f;
  unsigned int u = x.u32;
  return (ushort)((u + 0x7FFFu + ((u >> 16) & 1u)) >> 16);
}

// ---------------- weight convert + transpose: f32 [K][N] -> bf16 [N][K] ----------------
__global__ __launch_bounds__(256) void convT_k(const float* __restrict__ in, ushort* __restrict__ out,
                                               int K, int N, long inStride, long outStride)
{
  in  += (long)blockIdx.z * inStride;
  out += (long)blockIdx.z * outStride;
  __shared__ float tile[64][65];
  int n0 = blockIdx.x * 64, k0 = blockIdx.y * 64;
  int tid = threadIdx.x;
  int cc = tid & 63, rr = tid >> 6;
#pragma unroll
  for (int i = 0; i < 16; i++){
    int r = rr + i * 4;
    tile[r][cc] = in[(long)(k0 + r) * N + n0 + cc];
  }
  __syncthreads();
#pragma unroll
  for (int i = 0; i < 16; i++){
    int r = rr + i * 4;
    out[(long)(n0 + r) * K + k0 + cc] = f2b(tile[cc][r]);
  }
}

// ---------------- embedding (token-major x, b-major out_emb) ----------------
__global__ __launch_bounds__(256) void embed_k(const int* __restrict__ ids, const float* __restrict__ emb,
                                               const float* __restrict__ pe, float* __restrict__ x,
                                               float* __restrict__ oemb)
{
  int t = blockIdx.x, b = blockIdx.y, tid = threadIdx.x;
  int id = ids[b * SS + t];
  float4 ev = *((const float4*)(emb + (long)id * DD) + tid);
  float4 pv = *((const float4*)(pe  + (long)t  * DD) + tid);
  *((float4*)(x + (long)(t * BB + b) * DD) + tid) =
      make_float4(ev.x + pv.x, ev.y + pv.y, ev.z + pv.z, ev.w + pv.w);
  float* op = oemb + ((long)b * SS + t) * DD + tid * 4;   // d_out+4B: scalar stores
  op[0] = ev.x; op[1] = ev.y; op[2] = ev.z; op[3] = ev.w;
}

// ---------------- layernorm: f32 row -> bf16 row (row-indexed, token-major) ----------------
__global__ __launch_bounds__(256) void ln_k(const float* __restrict__ xin, const float* __restrict__ g,
                                            const float* __restrict__ bt, ushort* __restrict__ out, long row0)
{
  long row = row0 + blockIdx.x;
  int tid = threadIdx.x;
  const float* rp = xin + row * DD;
  float4 v = *(const float4*)(rp + tid * 4);
  float s1 = v.x + v.y + v.z + v.w;
  float s2 = v.x * v.x + v.y * v.y + v.z * v.z + v.w * v.w;
#pragma unroll
  for (int o = 32; o; o >>= 1){ s1 += __shfl_down(s1, o); s2 += __shfl_down(s2, o); }
  __shared__ float red[2][4];
  int wv = tid >> 6, lane = tid & 63;
  if (lane == 0){ red[0][wv] = s1; red[1][wv] = s2; }
  __syncthreads();
  s1 = red[0][0] + red[0][1] + red[0][2] + red[0][3];
  s2 = red[1][0] + red[1][1] + red[1][2] + red[1][3];
  float mean = s1 * (1.0f / DD);
  float var  = s2 * (1.0f / DD) - mean * mean;
  float rstd = rsqrtf(var + 1e-5f);
  float4 gv = *(const float4*)(g + tid * 4);
  float4 bv = *(const float4*)(bt + tid * 4);
  ushort4 o4;
  o4.x = f2b((v.x - mean) * rstd * gv.x + bv.x);
  o4.y = f2b((v.y - mean) * rstd * gv.y + bv.y);
  o4.z = f2b((v.z - mean) * rstd * gv.z + bv.z);
  o4.w = f2b((v.w - mean) * rstd * gv.w + bv.w);
  *(ushort4*)(out + row * DD + tid * 4) = o4;
}

// ---------------- shared epilogue (big GEMM path) ----------------
template<int EPI>
__device__ __forceinline__ void epi_store(float v, int grow, int ocol, void* Cv, int ldc,
                                          const float* Add, int t0, int l,
                                          ushort* kc, ushort* vc, ushort* qb)
{
  if constexpr (EPI == 1){
    float* Cf = (float*)Cv; long idx = (long)grow * ldc + ocol;
    Cf[idx] = v + Add[idx];
  } else if constexpr (EPI == 2){
    ushort* Cb = (ushort*)Cv; long idx = (long)grow * ldc + ocol;
    float tt = 0.7978845608028654f * (v + 0.044715f * v * v * v);
    Cb[idx] = f2b(0.5f * v * (1.0f + tanhf(tt)));
  } else if constexpr (EPI == 3){
    int t = t0 + (grow >> 2), b = grow & 3;
    ((float*)Cv)[((long)b * SS + t) * VV + ocol] = v;
  } else if constexpr (EPI == 4){
    if (ocol < DD){
      qb[((long)(t0 * BB + grow)) * DD + ocol] = f2b(v);
    } else {
      int t = t0 + (grow >> 2), b = grow & 3;
      int h = (ocol >> 6) & 15, d = ocol & 63;
      long dst = (((long)l * BB + b) * HH + h) * ((long)SS * DHH) + (long)t * DHH + d;
      if (ocol >= 2 * DD) vc[dst] = f2b(v); else kc[dst] = f2b(v);
    }
  }
}

// ---------------- big GEMM (BM=128): reg-staged, padded LDS, named-reg prefetch, split-K ----------------
template<int EPI>
__global__ __launch_bounds__(256) void gemm_k(const ushort* __restrict__ A, int lda,
                                              const ushort* __restrict__ BT,
                                              void* Cv, int ldc,
                                              const float* Add,
                                              int M, int N, int K, int gx,
                                              int l, int t0,
                                              ushort* kc, ushort* vc, ushort* qb,
                                              float* part, int KS)
{
  constexpr int BM  = 128;
  constexpr int MFR = 4;
  constexpr int NFR = 4;
  __shared__ ushort As[BM][72];
  __shared__ ushort Bs[128][72];
  int tid = threadIdx.x;
  int wv = tid >> 6, lane = tid & 63;
  int wm = wv >> 1, wn = wv & 1;

  int nwg = gridDim.x, orig = blockIdx.x;
  int wgid;
  if (nwg <= 1024){
    int qq = nwg >> 3, rr8 = nwg & 7, xcd = orig & 7;
    wgid = ((xcd < rr8) ? xcd * (qq + 1) : rr8 * (qq + 1) + (xcd - rr8) * qq) + (orig >> 3);
  } else {
    wgid = orig;
  }

  int gxy = gx * (N >> 7);
  int ksId = wgid / gxy;
  int rem  = wgid - ksId * gxy;
  int bx = rem % gx, by = rem / gx;
  int m0 = bx * BM, n0 = by * 128;
  int Kc = K / KS;
  int k_beg = ksId * Kc, k_end = k_beg + Kc;

  f32x4 acc[MFR][NFR];
  f32x4 zz = {0.f, 0.f, 0.f, 0.f};
#pragma unroll
  for (int m = 0; m < MFR; m++)
#pragma unroll
    for (int n = 0; n < NFR; n++) acc[m][n] = zz;

  int g4 = (lane >> 4) * 4;
  int rA = lane & 15;
  int arow = tid >> 3;
  int acol = (tid & 7) * 8;

  const ushort* Bp = BT + (long)(n0 + arow) * K + acol;
  long sB = 32 * (long)K;
  int gr0 = m0 + arow;       if (gr0 > M - 1) gr0 = M - 1;
  int gr1 = m0 + 32 + arow;  if (gr1 > M - 1) gr1 = M - 1;
  int gr2 = m0 + 64 + arow;  if (gr2 > M - 1) gr2 = M - 1;
  int gr3 = m0 + 96 + arow;  if (gr3 > M - 1) gr3 = M - 1;
  const ushort* Ap0 = A + (long)gr0 * lda + acol;
  const ushort* Ap1 = A + (long)gr1 * lda + acol;
  const ushort* Ap2 = A + (long)gr2 * lda + acol;
  const ushort* Ap3 = A + (long)gr3 * lda + acol;

  uint4 b0 = *(const uint4*)(Bp + k_beg);
  uint4 b1 = *(const uint4*)(Bp + sB + k_beg);
  uint4 b2 = *(const uint4*)(Bp + 2 * sB + k_beg);
  uint4 b3 = *(const uint4*)(Bp + 3 * sB + k_beg);
  uint4 a0 = *(const uint4*)(Ap0 + k_beg);
  uint4 a1 = *(const uint4*)(Ap1 + k_beg);
  uint4 a2 = *(const uint4*)(Ap2 + k_beg);
  uint4 a3 = *(const uint4*)(Ap3 + k_beg);

  for (int k0 = k_beg; k0 < k_end; k0 += 64){
    *(uint4*)&Bs[arow     ][acol] = b0;
    *(uint4*)&Bs[arow + 32][acol] = b1;
    *(uint4*)&Bs[arow + 64][acol] = b2;
    *(uint4*)&Bs[arow + 96][acol] = b3;
    *(uint4*)&As[arow     ][acol] = a0;
    *(uint4*)&As[arow + 32][acol] = a1;
    *(uint4*)&As[arow + 64][acol] = a2;
    *(uint4*)&As[arow + 96][acol] = a3;
    __syncthreads();
    int kn = k0 + 64;
    if (kn < k_end){
      b0 = *(const uint4*)(Bp + kn);
      b1 = *(const uint4*)(Bp + sB + kn);
      b2 = *(const uint4*)(Bp + 2 * sB + kn);
      b3 = *(const uint4*)(Bp + 3 * sB + kn);
      a0 = *(const uint4*)(Ap0 + kn);
      a1 = *(const uint4*)(Ap1 + kn);
      a2 = *(const uint4*)(Ap2 + kn);
      a3 = *(const uint4*)(Ap3 + kn);
    }
#pragma unroll
    for (int kk = 0; kk < 64; kk += 32){
      bf16x8 af[MFR], bfr[NFR];
#pragma unroll
      for (int m = 0; m < MFR; m++){
        int row = wm * 64 + m * 16 + rA;
        bf16x4v lo = *(const bf16x4v*)&As[row][kk + g4];
        bf16x4v hi = *(const bf16x4v*)&As[row][kk + 16 + g4];
        af[m] = __builtin_shufflevector(lo, hi, 0, 1, 2, 3, 4, 5, 6, 7);
      }
#pragma unroll
      for (int n = 0; n < NFR; n++){
        int row = wn * 64 + n * 16 + rA;
        bf16x4v lo = *(const bf16x4v*)&Bs[row][kk + g4];
        bf16x4v hi = *(const bf16x4v*)&Bs[row][kk + 16 + g4];
        bfr[n] = __builtin_shufflevector(lo, hi, 0, 1, 2, 3, 4, 5, 6, 7);
      }
#pragma unroll
      for (int m = 0; m < MFR; m++)
#pragma unroll
        for (int n = 0; n < NFR; n++)
          acc[m][n] = __builtin_amdgcn_mfma_f32_16x16x32_bf16(af[m], bfr[n], acc[m][n], 0, 0, 0);
    }
    __syncthreads();
  }

  int r4 = (lane >> 4) * 4;
#pragma unroll
  for (int m = 0; m < MFR; m++){
#pragma unroll
    for (int n = 0; n < NFR; n++){
      int orow = wm * 64 + m * 16 + r4;
      int ocol = n0 + wn * 64 + n * 16 + rA;
#pragma unroll
      for (int r = 0; r < 4; r++){
        int grow = m0 + orow + r;
        if (grow < M){
          if (KS > 1)
            part[(long)ksId * M * N + (long)grow * N + ocol] = acc[m][n][r];
          else
            epi_store<EPI>(acc[m][n][r], grow, ocol, Cv, ldc, Add, t0, l, kc, vc, qb);
        }
      }
    }
  }
}

// ---------------- split-K reduce (applies epilogue) ----------------
template<int EPI>
__global__ __launch_bounds__(256) void sred_k(const float* __restrict__ part, int KS, int M, int N,
                                              void* Cv, int ldc, const float* Add,
                                              int l, int t0, ushort* kc, ushort* vc, ushort* qb)
{
  long i = (long)blockIdx.x * 256 + threadIdx.x;
  long MN = (long)M * N;
  if (i >= MN) return;
  float v = 0.f;
  for (int s = 0; s < KS; s++) v += part[s * MN + i];
  int m = (int)(i / N), n = (int)(i - (long)m * N);
  epi_store<EPI>(v, m, n, Cv, ldc, Add, t0, l, kc, vc, qb);
}

// ---------------- decode GEMV (fallback path, M=4): one output column per wave ----------------
template<int TYPE>
__global__ __launch_bounds__(256) void dec_gemv_k(const float* xf, const ushort* ab,
                                                  const float* g, const float* bt,
                                                  const ushort* WT, float* x,
                                                  ushort* qb, ushort* kc, ushort* vc, ushort* gb,
                                                  int l, int pos)
{
  constexpr int K   = (TYPE == 3) ? FFF : DD;
  constexpr int NCH = K / 1024;
  int tid = threadIdx.x, wid = tid >> 6, lane = tid & 63;
  int n = blockIdx.x * 4 + wid;

  float acc[4] = {0.f, 0.f, 0.f, 0.f};

#pragma unroll
  for (int ch = 0; ch < NCH; ch++){
    int ks = ch * 1024 + lane * 16;
    float a[4][16];
    if constexpr (TYPE == 0 || TYPE == 2){
#pragma unroll
      for (int r = 0; r < 4; r++){
        const float* rp = xf + (long)(pos * BB + r) * DD + ks;
#pragma unroll
        for (int q = 0; q < 4; q++){
          float4 v = *(const float4*)(rp + q * 4);
          a[r][q*4+0] = v.x; a[r][q*4+1] = v.y; a[r][q*4+2] = v.z; a[r][q*4+3] = v.w;
        }
      }
      float gj[16], bj[16];
#pragma unroll
      for (int q = 0; q < 4; q++){
        float4 gv = *(const float4*)(g  + ks + q * 4);
        float4 bv = *(const float4*)(bt + ks + q * 4);
        gj[q*4+0]=gv.x; gj[q*4+1]=gv.y; gj[q*4+2]=gv.z; gj[q*4+3]=gv.w;
        bj[q*4+0]=bv.x; bj[q*4+1]=bv.y; bj[q*4+2]=bv.z; bj[q*4+3]=bv.w;
      }
#pragma unroll
      for (int r = 0; r < 4; r++){
        float s1 = 0.f, s2 = 0.f;
#pragma unroll
        for (int j = 0; j < 16; j++){ s1 += a[r][j]; s2 += a[r][j] * a[r][j]; }
#pragma unroll
        for (int o = 32; o; o >>= 1){ s1 += __shfl_xor(s1, o); s2 += __shfl_xor(s2, o); }
        float mean = s1 * (1.0f / DD);
        float var  = s2 * (1.0f / DD) - mean * mean;
        float rstd = rsqrtf(var + 1e-5f);
#pragma unroll
        for (int j = 0; j < 16; j++)
          a[r][j] = b2f(f2b((a[r][j] - mean) * rstd * gj[j] + bj[j]));
      }
    } else {
      constexpr int AD = (TYPE == 3) ? FFF : DD;
#pragma unroll
      for (int r = 0; r < 4; r++){
        const ushort* rp = ab + (long)(pos * BB + r) * AD + ks;
        uint4 pa = *(const uint4*)rp;
        uint4 pb = *(const uint4*)(rp + 8);
        const unsigned int w[8] = {pa.x, pa.y, pa.z, pa.w, pb.x, pb.y, pb.z, pb.w};
#pragma unroll
        for (int q = 0; q < 8; q++){
          a[r][q*2]   = b2f((ushort)(w[q] & 0xffff));
          a[r][q*2+1] = b2f((ushort)(w[q] >> 16));
        }
      }
    }
    {
      const ushort* wp = WT + (long)n * K + ks;
      uint4 pa = *(const uint4*)wp;
      uint4 pb = *(const uint4*)(wp + 8);
      const unsigned int w[8] = {pa.x, pa.y, pa.z, pa.w, pb.x, pb.y, pb.z, pb.w};
      float wf[16];
#pragma unroll
      for (int q = 0; q < 8; q++){
        wf[q*2]   = b2f((ushort)(w[q] & 0xffff));
        wf[q*2+1] = b2f((ushort)(w[q] >> 16));
      }
#pragma unroll
      for (int r = 0; r < 4; r++){
        float s = 0.f;
#pragma unroll
        for (int j = 0; j < 16; j++) s += a[r][j] * wf[j];
        acc[r] += s;
      }
    }
  }

#pragma unroll
  for (int r = 0; r < 4; r++)
#pragma unroll
    for (int o = 32; o; o >>= 1) acc[r] += __shfl_xor(acc[r], o);

  if (lane < 4){
    int r = lane;
    long Rrow = (long)(pos * BB + r);
    float v = acc[r];
    if constexpr (TYPE == 0){
      if (n < DD){
        qb[Rrow * DD + n] = f2b(v);
      } else if (n < 2 * DD){
        int h = (n - DD) >> 6, d = n & 63;
        kc[(((long)l * BB + r) * HH + h) * ((long)SS * DHH) + (long)pos * DHH + d] = f2b(v);
      } else {
        int h = (n - 2 * DD) >> 6, d = n & 63;
        vc[(((long)l * BB + r) * HH + h) * ((long)SS * DHH) + (long)pos * DHH + d] = f2b(v);
      }
    } else if constexpr (TYPE == 2){
      float tt = 0.7978845608028654f * (v + 0.044715f * v * v * v);
      gb[Rrow * FFF + n] = f2b(0.5f * v * (1.0f + tanhf(tt)));
    } else {
      long idx = Rrow * DD + n;
      x[idx] = x[idx] + v;
    }
  }
}

// ---------------- decode final (fallback): lnf + hid write + advance ----------------
__global__ __launch_bounds__(256) void dec_final_k(const float* xf, const float* g, const float* bt,
                                                   const float* pe, ushort* hid, float* x,
                                                   float* oemb, int pos)
{
  int wid = threadIdx.x >> 6, lane = threadIdx.x & 63;
  long R = (long)(pos * BB + wid);
  const float* rp = xf + R * DD + lane * 16;
  float a[16];
#pragma unroll
  for (int q = 0; q < 4; q++){
    float4 v = *(const float4*)(rp + q * 4);
    a[q*4+0] = v.x; a[q*4+1] = v.y; a[q*4+2] = v.z; a[q*4+3] = v.w;
  }
  float s1 = 0.f, s2 = 0.f;
#pragma unroll
  for (int j = 0; j < 16; j++){ s1 += a[j]; s2 += a[j] * a[j]; }
#pragma unroll
  for (int o = 32; o; o >>= 1){ s1 += __shfl_xor(s1, o); s2 += __shfl_xor(s2, o); }
  float mean = s1 * (1.0f / DD);
  float var  = s2 * (1.0f / DD) - mean * mean;
  float rstd = rsqrtf(var + 1e-5f);
  int pn = pos + 1;
#pragma unroll
  for (int j = 0; j < 16; j++){
    int d = lane * 16 + j;
    ushort hb = f2b((a[j] - mean) * rstd * g[d] + bt[d]);
    hid[R * DD + d] = hb;
    float hv = b2f(hb);
    oemb[((long)wid * SS + pn) * DD + d] = hv;
    x[((long)(pn * BB + wid)) * DD + d] = hv + pe[(long)pn * DD + d];
  }
}

// ================= cooperative decode: all 5 latent steps in ONE kernel =================
struct DecParams {
  const float* pe;
  float* x;
  ushort* qb; ushort* kc; ushort* vc; ushort* gb; ushort* ob;
  ushort* hid; float* oemb;
  const ushort* wqkvT; const ushort* woT; const ushort* w1T; const ushort* w2T;
  const float* ln1g; const float* ln1b; const float* ln2g; const float* ln2b;
  const float* lnfg; const float* lnfb;
};

template<int TYPE>  // 0: LN1->qkv->qb/kc/vc ; 2: LN2->W1->gelu->gb
__device__ __forceinline__ void dec_gemv_ln_phase(const DecParams& p, int l, int pos,
                                                  int gw, int nw, int lane)
{
  constexpr int NCOLS = (TYPE == 0) ? 3 * DD : FFF;
  const ushort* WT = (TYPE == 0) ? p.wqkvT + (long)l * 3 * DD * DD
                                 : p.w1T   + (long)l * FFF * DD;
  const float* g  = ((TYPE == 0) ? p.ln1g : p.ln2g) + l * DD;
  const float* bt = ((TYPE == 0) ? p.ln1b : p.ln2b) + l * DD;
  int ks = lane * 16;
  float a[4][16];
#pragma unroll
  for (int r = 0; r < 4; r++){
    const float* rp = p.x + (long)(pos * BB + r) * DD + ks;
#pragma unroll
    for (int q = 0; q < 4; q++){
      float4 v = *(const float4*)(rp + q * 4);
      a[r][q*4+0] = v.x; a[r][q*4+1] = v.y; a[r][q*4+2] = v.z; a[r][q*4+3] = v.w;
    }
  }
  float gj[16], bj[16];
#pragma unroll
  for (int q = 0; q < 4; q++){
    float4 gv = *(const float4*)(g  + ks + q * 4);
    float4 bv = *(const float4*)(bt + ks + q * 4);
    gj[q*4+0]=gv.x; gj[q*4+1]=gv.y; gj[q*4+2]=gv.z; gj[q*4+3]=gv.w;
    bj[q*4+0]=bv.x; bj[q*4+1]=bv.y; bj[q*4+2]=bv.z; bj[q*4+3]=bv.w;
  }
#pragma unroll
  for (int r = 0; r < 4; r++){
    float s1 = 0.f, s2 = 0.f;
#pragma unroll
    for (int j = 0; j < 16; j++){ s1 += a[r][j]; s2 += a[r][j] * a[r][j]; }
#pragma unroll
    for (int o = 32; o; o >>= 1){ s1 += __shfl_xor(s1, o); s2 += __shfl_xor(s2, o); }
    float mean = s1 * (1.0f / DD);
    float var  = s2 * (1.0f / DD) - mean * mean;
    float rstd = rsqrtf(var + 1e-5f);
#pragma unroll
    for (int j = 0; j < 16; j++)
      a[r][j] = b2f(f2b((a[r][j] - mean) * rstd * gj[j] + bj[j]));   // match bf16 hbuf path
  }
  for (int n = gw; n < NCOLS; n += nw){
    const ushort* wp = WT + (long)n * DD + ks;
    uint4 pa = *(const uint4*)wp;
    uint4 pb = *(const uint4*)(wp + 8);
    const unsigned int w[8] = {pa.x, pa.y, pa.z, pa.w, pb.x, pb.y, pb.z, pb.w};
    float wf[16];
#pragma unroll
    for (int q = 0; q < 8; q++){
      wf[q*2]   = b2f((ushort)(w[q] & 0xffff));
      wf[q*2+1] = b2f((ushort)(w[q] >> 16));
    }
    float acc[4];
#pragma unroll
    for (int r = 0; r < 4; r++){
      float s = 0.f;
#pragma unroll
      for (int j = 0; j < 16; j++) s += a[r][j] * wf[j];
      acc[r] = s;
    }
#pragma unroll
    for (int r = 0; r < 4; r++)
#pragma unroll
      for (int o = 32; o; o >>= 1) acc[r] += __shfl_xor(acc[r], o);
    if (lane < 4){
      int r = lane;
      long Rrow = (long)(pos * BB + r);
      float v = acc[r];
      if constexpr (TYPE == 0){
        if (n < DD){
          p.qb[Rrow * DD + n] = f2b(v);
        } else if (n < 2 * DD){
          int h = (n - DD) >> 6, d = n & 63;
          p.kc[(((long)l * BB + r) * HH + h) * ((long)SS * DHH) + (long)pos * DHH + d] = f2b(v);
        } else {
          int h = (n - 2 * DD) >> 6, d = n & 63;
          p.vc[(((long)l * BB + r) * HH + h) * ((long)SS * DHH) + (long)pos * DHH + d] = f2b(v);
        }
      } else {
        float tt = 0.7978845608028654f * (v + 0.044715f * v * v * v);
        p.gb[Rrow * FFF + n] = f2b(0.5f * v * (1.0f + tanhf(tt)));
      }
    }
  }
}

template<int TYPE>  // 1: ob->Wo->x+= ; 3: gb(K=4096)->W2->x+=
__device__ __forceinline__ void dec_gemv_res_phase(const DecParams& p, int l, int pos,
                                                   int gw, int nw, int lane)
{
  constexpr int K   = (TYPE == 3) ? FFF : DD;
  constexpr int NCH = K / 1024;
  const ushort* WT = (TYPE == 1) ? p.woT + (long)l * DD * DD : p.w2T + (long)l * DD * FFF;
  const ushort* ab = (TYPE == 1) ? p.ob : p.gb;
  for (int n = gw; n < DD; n += nw){
    float acc[4] = {0.f, 0.f, 0.f, 0.f};
#pragma unroll
    for (int ch = 0; ch < NCH; ch++){
      int ks = ch * 1024 + lane * 16;
      const ushort* wp = WT + (long)n * K + ks;
      uint4 wa = *(const uint4*)wp;
      uint4 wb = *(const uint4*)(wp + 8);
      const unsigned int w[8] = {wa.x, wa.y, wa.z, wa.w, wb.x, wb.y, wb.z, wb.w};
      float wf[16];
#pragma unroll
      for (int q = 0; q < 8; q++){
        wf[q*2]   = b2f((ushort)(w[q] & 0xffff));
        wf[q*2+1] = b2f((ushort)(w[q] >> 16));
      }
#pragma unroll
      for (int r = 0; r < 4; r++){
        const ushort* rp = ab + (long)(pos * BB + r) * K + ks;
        uint4 xa = *(const uint4*)rp;
        uint4 xb = *(const uint4*)(rp + 8);
        const unsigned int xw[8] = {xa.x, xa.y, xa.z, xa.w, xb.x, xb.y, xb.z, xb.w};
        float s = 0.f;
#pragma unroll
        for (int q = 0; q < 8; q++){
          s += b2f((ushort)(xw[q] & 0xffff)) * wf[q*2];
          s += b2f((ushort)(xw[q] >> 16))    * wf[q*2+1];
        }
        acc[r] += s;
      }
    }
#pragma unroll
    for (int r = 0; r < 4; r++)
#pragma unroll
      for (int o = 32; o; o >>= 1) acc[r] += __shfl_xor(acc[r], o);
    if (lane < 4){
      long idx = (long)(pos * BB + lane) * DD + n;
      p.x[idx] = p.x[idx] + acc[lane];
    }
  }
}

__global__ __launch_bounds__(256) void dec_all_k(DecParams p)
{
  cooperative_groups::grid_group grid = cooperative_groups::this_grid();
  int tid = threadIdx.x, wid = tid >> 6, lane = tid & 63;
  int gw = blockIdx.x * 4 + wid;
  int nw = gridDim.x * 4;
  __shared__ float qs[4][64];
  __shared__ float ps[4][80];

  for (int step = 0; step < 5; step++){
    int pos = 64 + step;
    for (int l = 0; l < LL; l++){
      dec_gemv_ln_phase<0>(p, l, pos, gw, nw, lane);
      __threadfence(); grid.sync(); __threadfence();
      if (gw < BB * HH){
        int b = gw >> 4, h = gw & 15;
        long kvoff = (((long)l * BB + b) * HH + h) * ((long)SS * DHH);
        const ushort* kb = p.kc + kvoff;
        const ushort* vb = p.vc + kvoff;
        qs[wid][lane] = b2f(p.qb[((long)(pos * BB + b)) * DD + h * DHH + lane]);
        int nk = pos + 1;
        float m = -3.0e38f;
        for (int key = lane; key < nk; key += 64){
          const ushort* kp = kb + (long)key * DHH;
          float s = 0.f;
#pragma unroll
          for (int j = 0; j < 8; j++){
            uint4 kvv = *(const uint4*)(kp + j * 8);
            s += qs[wid][j*8+0] * b2f((ushort)(kvv.x & 0xffff));
            s += qs[wid][j*8+1] * b2f((ushort)(kvv.x >> 16));
            s += qs[wid][j*8+2] * b2f((ushort)(kvv.y & 0xffff));
            s += qs[wid][j*8+3] * b2f((ushort)(kvv.y >> 16));
            s += qs[wid][j*8+4] * b2f((ushort)(kvv.z & 0xffff));
            s += qs[wid][j*8+5] * b2f((ushort)(kvv.z >> 16));
            s += qs[wid][j*8+6] * b2f((ushort)(kvv.w & 0xffff));
            s += qs[wid][j*8+7] * b2f((ushort)(kvv.w >> 16));
          }
          s *= 0.125f;
          ps[wid][key] = s;
          m = fmaxf(m, s);
        }
#pragma unroll
        for (int off = 32; off; off >>= 1) m = fmaxf(m, __shfl_xor(m, off));
        float ssum = 0.f;
        for (int key = lane; key < nk; key += 64){
          float pv = expf(ps[wid][key] - m);
          ps[wid][key] = pv;
          ssum += pv;
        }
#pragma unroll
        for (int off = 32; off; off >>= 1) ssum += __shfl_xor(ssum, off);
        float accv = 0.f;
        for (int key = 0; key < nk; key++)
          accv += ps[wid][key] * b2f(vb[(long)key * DHH + lane]);
        p.ob[((long)(pos * BB + b)) * DD + h * DHH + lane] = f2b(accv / ssum);
      }
      __threadfence(); grid.sync(); __threadfence();
      dec_gemv_res_phase<1>(p, l, pos, gw, nw, lane);
      __threadfence(); grid.sync(); __threadfence();
      dec_gemv_ln_phase<2>(p, l, pos, gw, nw, lane);
      __threadfence(); grid.sync(); __threadfence();
      dec_gemv_res_phase<3>(p, l, pos, gw, nw, lane);
      __threadfence(); grid.sync(); __threadfence();
    }
    if (blockIdx.x == 0){
      long R = (long)(pos * BB + wid);
      const float* rp = p.x + R * DD + lane * 16;
      float a[16];
#pragma unroll
      for (int q = 0; q < 4; q++){
        float4 v = *(const float4*)(rp + q * 4);
        a[q*4+0] = v.x; a[q*4+1] = v.y; a[q*4+2] = v.z; a[q*4+3] = v.w;
      }
      float s1 = 0.f, s2 = 0.f;
#pragma unroll
      for (int j = 0; j < 16; j++){ s1 += a[j]; s2 += a[j] * a[j]; }
#pragma unroll
      for (int o = 32; o; o >>= 1){ s1 += __shfl_xor(s1, o); s2 += __shfl_xor(s2, o); }
      float mean = s1 * (1.0f / DD);
      float var  = s2 * (1.0f / DD) - mean * mean;
      float rstd = rsqrtf(var + 1e-5f);
      int pn = pos + 1;
#pragma unroll
      for (int j = 0; j < 16; j++){
        int d = lane * 16 + j;
        ushort hb = f2b((a[j] - mean) * rstd * p.lnfg[d] + p.lnfb[d]);
        p.hid[R * DD + d] = hb;
        float hv = b2f(hb);
        p.oemb[((long)wid * SS + pn) * DD + d] = hv;
        p.x[((long)(pn * BB + wid)) * DD + d] = hv + p.pe[(long)pn * DD + d];
      }
    }
    __threadfence(); grid.sync(); __threadfence();
  }
}

// ---------------- attention (token-major q/o, cached k/v) — round-11 measured-best form ----------------
__global__ __launch_bounds__(256) void attn_k(const ushort* __restrict__ qb, const ushort* __restrict__ kc,
                                              const ushort* __restrict__ vc, ushort* __restrict__ o,
                                              int l, int t0, int Tc)
{
  __shared__ float sc[4][512];
  __shared__ float qs[4][64];
  int tid = threadIdx.x, wv = tid >> 6, lane = tid & 63;
  int b = blockIdx.z, h = blockIdx.y;
  int qrow = blockIdx.x * 4 + wv;
  bool act = qrow < Tc;
  int tq = t0 + qrow;
  long kvoff = (((long)l * BB + b) * HH + h) * ((long)SS * DHH);
  const ushort* kb = kc + kvoff;
  const ushort* vb = vc + kvoff;
  if (act) qs[wv][lane] = b2f(qb[((long)(tq * BB + b)) * DD + h * DHH + lane]);
  __syncthreads();
  int nk = act ? (tq + 1) : 0;
  float m = -3.0e38f;
  for (int key = lane; key < nk; key += 64){
    const ushort* kp = kb + (long)key * DHH;
    float s = 0.f;
#pragma unroll
    for (int j = 0; j < 8; j++){
      uint4 kvv = *(const uint4*)(kp + j * 8);
      s += qs[wv][j*8+0] * b2f((ushort)(kvv.x & 0xffff));
      s += qs[wv][j*8+1] * b2f((ushort)(kvv.x >> 16));
      s += qs[wv][j*8+2] * b2f((ushort)(kvv.y & 0xffff));
      s += qs[wv][j*8+3] * b2f((ushort)(kvv.y >> 16));
      s += qs[wv][j*8+4] * b2f((ushort)(kvv.z & 0xffff));
      s += qs[wv][j*8+5] * b2f((ushort)(kvv.z >> 16));
      s += qs[wv][j*8+6] * b2f((ushort)(kvv.w & 0xffff));
      s += qs[wv][j*8+7] * b2f((ushort)(kvv.w >> 16));
    }
    s *= 0.125f;
    sc[wv][key] = s;
    m = fmaxf(m, s);
  }
#pragma unroll
  for (int off = 32; off; off >>= 1) m = fmaxf(m, __shfl_xor(m, off));
  float ssum = 0.f;
  for (int key = lane; key < nk; key += 64){
    float p = expf(sc[wv][key] - m);
    sc[wv][key] = p;
    ssum += p;
  }
#pragma unroll
  for (int off = 32; off; off >>= 1) ssum += __shfl_xor(ssum, off);
  __syncthreads();
  float accv = 0.f;
  int key = 0;
  for (; key + 3 < nk; key += 4){
    float p0 = sc[wv][key],     p1 = sc[wv][key + 1];
    float p2 = sc[wv][key + 2], p3 = sc[wv][key + 3];
    float v0 = b2f(vb[(long)key * DHH + lane]);
    float v1 = b2f(vb[(long)(key + 1) * DHH + lane]);
    float v2 = b2f(vb[(long)(key + 2) * DHH + lane]);
    float v3 = b2f(vb[(long)(key + 3) * DHH + lane]);
    accv += p0 * v0 + p1 * v1 + p2 * v2 + p3 * v3;
  }
  for (; key < nk; key++)
    accv += sc[wv][key] * b2f(vb[(long)key * DHH + lane]);
  if (act) o[((long)(tq * BB + b)) * DD + h * DHH + lane] = f2b(accv / ssum);
}

// ---------------- feedback (chunk-0 boundary only) ----------------
__global__ __launch_bounds__(256) void advance_k(const ushort* __restrict__ hid, const float* __restrict__ pe,
                                                 float* __restrict__ x, float* __restrict__ oemb, int pos)
{
  int d = blockIdx.x * 256 + threadIdx.x;
  int b = blockIdx.y;
  float hv = b2f(hid[((long)((pos - 1) * BB + b)) * DD + d]);
  oemb[((long)b * SS + pos) * DD + d] = hv;
  x[((long)(pos * BB + b)) * DD + d] = hv + pe[(long)pos * DD + d];
}

// ---------------- loss (float4 logits loads; head 0..2 + tail 31999 scalar) ----------------
__global__ __launch_bounds__(256) void loss_rows_k(const float* __restrict__ logits, const int* __restrict__ labels,
                                                   float* __restrict__ rowloss)
{
  int t = blockIdx.x, b = blockIdx.y, tid = threadIdx.x;
  const float* row = logits + ((long)b * SS + t) * VV;
  float m = -3.0e38f, s = 0.f;
  auto upd = [&](float v){
    if (v > m){ s = s * expf(m - v) + 1.f; m = v; }
    else s += expf(v - m);
  };
  if (tid < 3) upd(row[tid]);
  if (tid == 3) upd(row[VV - 1]);
  const float4* vrow = (const float4*)(row + 3);
  for (int i = tid; i < 7999; i += 256){
    float4 v = vrow[i];
    upd(v.x); upd(v.y); upd(v.z); upd(v.w);
  }
#pragma unroll
  for (int off = 32; off; off >>= 1){
    float om = __shfl_xor(m, off), os = __shfl_xor(s, off);
    float nm = fmaxf(m, om);
    s = s * expf(m - nm) + os * expf(om - nm);
    m = nm;
  }
  __shared__ float sm[4], ssb[4];
  if ((tid & 63) == 0){ sm[tid >> 6] = m; ssb[tid >> 6] = s; }
  __syncthreads();
  if (tid == 0){
    float M = fmaxf(fmaxf(sm[0], sm[1]), fmaxf(sm[2], sm[3]));
    float S = ssb[0] * expf(sm[0] - M) + ssb[1] * expf(sm[1] - M)
            + ssb[2] * expf(sm[2] - M) + ssb[3] * expf(sm[3] - M);
    int lab = labels[b * SS + t + 1];
    rowloss[b * (SS - 1) + t] = (M + logf(S)) - row[lab];
  }
}

__global__ __launch_bounds__(256) void loss_final_k(const float* __restrict__ rowloss, float* __restrict__ out)
{
  int tid = threadIdx.x;
  float s = 0.f;
  for (int i = tid; i < BB * (SS - 1); i += 256) s += rowloss[i];
#pragma unroll
  for (int o = 32; o; o >>= 1) s += __shfl_down(s, o);
  __shared__ float red[4];
  if ((tid & 63) == 0) red[tid >> 6] = s;
  __syncthreads();
  if (tid == 0) out[0] = (red[0] + red[1] + red[2] + red[3]) / (float)(BB * (SS - 1));
}

// ---------------- host ----------------
static inline int cdiv_i(int a, int b){ return (a + b - 1) / b; }

extern "C" void kernel_launch(void* const* d_in, const int* in_sizes, int n_in,
                              void* d_out, int out_size, void* d_ws, size_t ws_size,
                              hipStream_t stream)
{
  (void)in_sizes; (void)n_in; (void)out_size; (void)ws_size;
  const int*   ids    = (const int*)d_in[0];
  const int*   labels = (const int*)d_in[2];
  const float* emb    = (const float*)d_in[4];
  const float* pe     = (const float*)d_in[5];
  const float* Wqkv   = (const float*)d_in[6];
  const float* Wo     = (const float*)d_in[7];
  const float* W1     = (const float*)d_in[8];
  const float* W2     = (const float*)d_in[9];
  const float* ln1g   = (const float*)d_in[10];
  const float* ln1b   = (const float*)d_in[11];
  const float* ln2g   = (const float*)d_in[12];
  const float* ln2b   = (const float*)d_in[13];
  const float* lnfg   = (const float*)d_in[14];
  const float* lnfb   = (const float*)d_in[15];
  const float* lm     = (const float*)d_in[16];

  float* out_loss   = (float*)d_out;
  float* out_emb    = out_loss + 1;
  float* out_logits = out_emb + (size_t)BB * SS * DD;

  char* wsp = (char*)d_ws;
  size_t off = 0;
  auto alloc = [&](size_t bytes) -> void* {
    void* p = wsp + off; off += (bytes + 255) & ~(size_t)255; return p;
  };
  ushort* wqkvT = (ushort*)alloc((size_t)LL * 3 * DD * DD * 2);
  ushort* woT   = (ushort*)alloc((size_t)LL * DD * DD * 2);
  ushort* w1T   = (ushort*)alloc((size_t)LL * FFF * DD * 2);
  ushort* w2T   = (ushort*)alloc((size_t)LL * DD * FFF * 2);
  ushort* lmT   = (ushort*)alloc((size_t)VV * DD * 2);
  float*  x     = (float*)alloc((size_t)BB * SS * DD * 4);
  ushort* hbuf  = (ushort*)alloc((size_t)BB * SS * DD * 2);
  ushort* qbuf  = (ushort*)alloc((size_t)BB * SS * DD * 2);
  ushort* obuf  = (ushort*)alloc((size_t)BB * SS * DD * 2);
  ushort* gbuf  = (ushort*)alloc((size_t)BB * SS * FFF * 2);
  ushort* hid   = (ushort*)alloc((size_t)BB * SS * DD * 2);
  ushort* kcache= (ushort*)alloc((size_t)LL * BB * SS * DD * 2);
  ushort* vcache= (ushort*)alloc((size_t)LL * BB * SS * DD * 2);
  float*  part  = (float*)alloc((size_t)17 * 1024 * 1024);
  float*  rowls = (float*)alloc((size_t)BB * (SS - 1) * 4);

  convT_k<<<dim3(3 * DD / 64, DD / 64, LL), dim3(256), 0, stream>>>(Wqkv, wqkvT, DD, 3 * DD, (long)DD * 3 * DD, (long)3 * DD * DD);
  convT_k<<<dim3(DD / 64, DD / 64, LL),     dim3(256), 0, stream>>>(Wo,   woT,  DD, DD,     (long)DD * DD,     (long)DD * DD);
  convT_k<<<dim3(FFF / 64, DD / 64, LL),    dim3(256), 0, stream>>>(W1,   w1T,  DD, FFF,    (long)DD * FFF,    (long)FFF * DD);
  convT_k<<<dim3(DD / 64, FFF / 64, LL),    dim3(256), 0, stream>>>(W2,   w2T,  FFF, DD,    (long)FFF * DD,    (long)DD * FFF);
  convT_k<<<dim3(VV / 64, DD / 64, 1),      dim3(256), 0, stream>>>(lm,   lmT,  DD, VV,     0, 0);

  embed_k<<<dim3(SS, BB), dim3(256), 0, stream>>>(ids, emb, pe, x, out_emb);

  auto g128 = [&](int epi, const ushort* A, int lda, const ushort* BT, void* C, int ldc,
                  const float* Add, int M, int N, int K, int l, int t0, int KS){
    int gx = cdiv_i(M, 128);
    int nwg = gx * (N >> 7) * KS;
    if (epi == 1) gemm_k<1><<<nwg, 256, 0, stream>>>(A, lda, BT, C, ldc, Add, M, N, K, gx, l, t0, kcache, vcache, qbuf, part, KS);
    if (epi == 2) gemm_k<2><<<nwg, 256, 0, stream>>>(A, lda, BT, C, ldc, Add, M, N, K, gx, l, t0, kcache, vcache, qbuf, part, KS);
    if (epi == 3) gemm_k<3><<<nwg, 256, 0, stream>>>(A, lda, BT, C, ldc, Add, M, N, K, gx, l, t0, kcache, vcache, qbuf, part, KS);
    if (epi == 4) gemm_k<4><<<nwg, 256, 0, stream>>>(A, lda, BT, C, ldc, Add, M, N, K, gx, l, t0, kcache, vcache, qbuf, part, KS);
    if (KS > 1){
      int nred = cdiv_i(M * N, 256);
      if (epi == 1) sred_k<1><<<nred, 256, 0, stream>>>(part, KS, M, N, C, ldc, Add, l, t0, kcache, vcache, qbuf);
      if (epi == 2) sred_k<2><<<nred, 256, 0, stream>>>(part, KS, M, N, C, ldc, Add, l, t0, kcache, vcache, qbuf);
      if (epi == 4) sred_k<4><<<nred, 256, 0, stream>>>(part, KS, M, N, C, ldc, Add, l, t0, kcache, vcache, qbuf);
    }
  };

  auto big_chunk = [&](int t0, int Tc){
    int M = Tc * BB;
    long roff = (long)t0 * BB;
    bool small = (M <= 256);
    int ksQKV = small ? 4 : 1;
    int ksWO  = small ? 8 : 2;
    int ksW1  = small ? 4 : 1;
    int ksW2  = small ? 8 : 2;
    for (int l = 0; l < LL; l++){
      ln_k<<<dim3(M), dim3(256), 0, stream>>>(x, ln1g + l * DD, ln1b + l * DD, hbuf, roff);
      g128(4, hbuf + roff * DD, DD, wqkvT + (long)l * 3 * DD * DD, nullptr, 0, nullptr, M, 3 * DD, DD, l, t0, ksQKV);
      attn_k<<<dim3(cdiv_i(Tc, 4), HH, BB), dim3(256), 0, stream>>>(qbuf, kcache, vcache, obuf, l, t0, Tc);
      g128(1, obuf + roff * DD, DD, woT + (long)l * DD * DD, x + roff * DD, DD, x + roff * DD, M, DD, DD, l, t0, ksWO);
      ln_k<<<dim3(M), dim3(256), 0, stream>>>(x, ln2g + l * DD, ln2b + l * DD, hbuf, roff);
      g128(2, hbuf + roff * DD, DD, w1T + (long)l * FFF * DD, gbuf + roff * FFF, FFF, nullptr, M, FFF, DD, l, t0, ksW1);
      g128(1, gbuf + roff * FFF, FFF, w2T + (long)l * DD * FFF, x + roff * DD, DD, x + roff * DD, M, DD, FFF, l, t0, ksW2);
    }
    ln_k<<<dim3(M), dim3(256), 0, stream>>>(x, lnfg, lnfb, hid, roff);
  };

  // ---- chunk 0: prefill [0,64) ----
  big_chunk(0, 64);
  advance_k<<<dim3(DD / 256, BB), dim3(256), 0, stream>>>(hid, pe, x, out_emb, 64);

  // ---- decode steps 64..68: cooperative kernel (256 blocks = 1/CU, always co-resident) ----
  DecParams dp;
  dp.pe = pe; dp.x = x; dp.qb = qbuf; dp.kc = kcache; dp.vc = vcache; dp.gb = gbuf;
  dp.ob = obuf; dp.hid = hid; dp.oemb = out_emb;
  dp.wqkvT = wqkvT; dp.woT = woT; dp.w1T = w1T; dp.w2T = w2T;
  dp.ln1g = ln1g; dp.ln1b = ln1b; dp.ln2g = ln2g; dp.ln2b = ln2b;
  dp.lnfg = lnfg; dp.lnfb = lnfb;
  void* dargs[] = { (void*)&dp };
  hipError_t coopErr = hipLaunchCooperativeKernel((const void*)dec_all_k, dim3(256), dim3(256),
                                                  dargs, 0, stream);
  if (coopErr != hipSuccess){
    // deterministic fallback: proven multi-kernel decode
    for (int step = 0; step < 5; step++){
      int pos = 64 + step;
      for (int l = 0; l < LL; l++){
        dec_gemv_k<0><<<dim3(3 * DD / 4), dim3(256), 0, stream>>>(x, nullptr, ln1g + l * DD, ln1b + l * DD,
            wqkvT + (long)l * 3 * DD * DD, nullptr, qbuf, kcache, vcache, nullptr, l, pos);
        attn_k<<<dim3(1, HH, BB), dim3(64), 0, stream>>>(qbuf, kcache, vcache, obuf, l, pos, 1);
        dec_gemv_k<1><<<dim3(DD / 4), dim3(256), 0, stream>>>(nullptr, obuf, nullptr, nullptr,
            woT + (long)l * DD * DD, x, nullptr, nullptr, nullptr, nullptr, l, pos);
        dec_gemv_k<2><<<dim3(FFF / 4), dim3(256), 0, stream>>>(x, nullptr, ln2g + l * DD, ln2b + l * DD,
            w1T + (long)l * FFF * DD, nullptr, nullptr, nullptr, nullptr, gbuf, l, pos);
        dec_gemv_k<3><<<dim3(DD / 4), dim3(256), 0, stream>>>(nullptr, gbuf, nullptr, nullptr,
            w2T + (long)l * DD * FFF, x, nullptr, nullptr, nullptr, nullptr, l, pos);
      }
      dec_final_k<<<dim3(1), dim3(256), 0, stream>>>(x, lnfg, lnfb, pe, hid, x, out_emb, pos);
    }
  }

  // ---- chunk 6: prefill [69,512) ----
  big_chunk(69, 512 - 69);

  // single deferred lm_head over all positions (round-11 measured-best kernel)
  g128(3, hid, DD, lmT, out_logits, 0, nullptr, BB * SS, VV, DD, 0, 0, 1);

  loss_rows_k<<<dim3(SS - 1, BB), dim3(256), 0, stream>>>(out_logits, labels, rowls);
  loss_final_k<<<dim3(1), dim3(256), 0, stream>>>(rowls, out_loss);
}

// Round 16
// 2826.013 us; speedup vs baseline: 3.3706x; 3.3706x over previous
//
#include <hip/hip_runtime.h>

static constexpr int BB  = 4;
static constexpr int SS  = 512;
static constexpr int DD  = 1024;
static constexpr int HH  = 16;
static constexpr int LL  = 4;
static constexpr int VV  = 32000;
static constexpr int DHH = 64;
static constexpr int FFF = 4096;

typedef short bf16x8  __attribute__((ext_vector_type(8)));
typedef short bf16x4v __attribute__((ext_vector_type(4)));
typedef float f32x4   __attribute__((ext_vector_type(4)));

__device__ __forceinline__ float b2f(ushort u){
  union { float f; unsigned int u32; } x; x.u32 = ((unsigned int)u) << 16; return x.f;
}
__device__ __forceinline__ ushort f2b(float f){
  union { float f; unsigned int u32; } x; x.f = f;
  unsigned int u = x.u32;
  return (ushort)((u + 0x7FFFu + ((u >> 16) & 1u)) >> 16);
}

// ---------------- weight convert + transpose: f32 [K][N] -> bf16 [N][K] ----------------
__global__ __launch_bounds__(256) void convT_k(const float* __restrict__ in, ushort* __restrict__ out,
                                               int K, int N, long inStride, long outStride)
{
  in  += (long)blockIdx.z * inStride;
  out += (long)blockIdx.z * outStride;
  __shared__ float tile[64][65];
  int n0 = blockIdx.x * 64, k0 = blockIdx.y * 64;
  int tid = threadIdx.x;
  int cc = tid & 63, rr = tid >> 6;
#pragma unroll
  for (int i = 0; i < 16; i++){
    int r = rr + i * 4;
    tile[r][cc] = in[(long)(k0 + r) * N + n0 + cc];
  }
  __syncthreads();
#pragma unroll
  for (int i = 0; i < 16; i++){
    int r = rr + i * 4;
    out[(long)(n0 + r) * K + k0 + cc] = f2b(tile[cc][r]);
  }
}

// ---------------- embedding (token-major x, b-major out_emb) ----------------
__global__ __launch_bounds__(256) void embed_k(const int* __restrict__ ids, const float* __restrict__ emb,
                                               const float* __restrict__ pe, float* __restrict__ x,
                                               float* __restrict__ oemb)
{
  int t = blockIdx.x, b = blockIdx.y, tid = threadIdx.x;
  int id = ids[b * SS + t];
  float4 ev = *((const float4*)(emb + (long)id * DD) + tid);
  float4 pv = *((const float4*)(pe  + (long)t  * DD) + tid);
  *((float4*)(x + (long)(t * BB + b) * DD) + tid) =
      make_float4(ev.x + pv.x, ev.y + pv.y, ev.z + pv.z, ev.w + pv.w);
  float* op = oemb + ((long)b * SS + t) * DD + tid * 4;   // d_out+4B: scalar stores
  op[0] = ev.x; op[1] = ev.y; op[2] = ev.z; op[3] = ev.w;
}

// ---------------- layernorm: f32 row -> bf16 row (row-indexed, token-major) ----------------
__global__ __launch_bounds__(256) void ln_k(const float* __restrict__ xin, const float* __restrict__ g,
                                            const float* __restrict__ bt, ushort* __restrict__ out, long row0)
{
  long row = row0 + blockIdx.x;
  int tid = threadIdx.x;
  const float* rp = xin + row * DD;
  float4 v = *(const float4*)(rp + tid * 4);
  float s1 = v.x + v.y + v.z + v.w;
  float s2 = v.x * v.x + v.y * v.y + v.z * v.z + v.w * v.w;
#pragma unroll
  for (int o = 32; o; o >>= 1){ s1 += __shfl_down(s1, o); s2 += __shfl_down(s2, o); }
  __shared__ float red[2][4];
  int wv = tid >> 6, lane = tid & 63;
  if (lane == 0){ red[0][wv] = s1; red[1][wv] = s2; }
  __syncthreads();
  s1 = red[0][0] + red[0][1] + red[0][2] + red[0][3];
  s2 = red[1][0] + red[1][1] + red[1][2] + red[1][3];
  float mean = s1 * (1.0f / DD);
  float var  = s2 * (1.0f / DD) - mean * mean;
  float rstd = rsqrtf(var + 1e-5f);
  float4 gv = *(const float4*)(g + tid * 4);
  float4 bv = *(const float4*)(bt + tid * 4);
  ushort4 o4;
  o4.x = f2b((v.x - mean) * rstd * gv.x + bv.x);
  o4.y = f2b((v.y - mean) * rstd * gv.y + bv.y);
  o4.z = f2b((v.z - mean) * rstd * gv.z + bv.z);
  o4.w = f2b((v.w - mean) * rstd * gv.w + bv.w);
  *(ushort4*)(out + row * DD + tid * 4) = o4;
}

// ---------------- shared epilogue (big GEMM path) ----------------
template<int EPI>
__device__ __forceinline__ void epi_store(float v, int grow, int ocol, void* Cv, int ldc,
                                          const float* Add, int t0, int l,
                                          ushort* kc, ushort* vc, ushort* qb)
{
  if constexpr (EPI == 1){
    float* Cf = (float*)Cv; long idx = (long)grow * ldc + ocol;
    Cf[idx] = v + Add[idx];
  } else if constexpr (EPI == 2){
    ushort* Cb = (ushort*)Cv; long idx = (long)grow * ldc + ocol;
    float tt = 0.7978845608028654f * (v + 0.044715f * v * v * v);
    Cb[idx] = f2b(0.5f * v * (1.0f + tanhf(tt)));
  } else if constexpr (EPI == 3){
    int t = t0 + (grow >> 2), b = grow & 3;
    ((float*)Cv)[((long)b * SS + t) * VV + ocol] = v;
  } else if constexpr (EPI == 4){
    if (ocol < DD){
      qb[((long)(t0 * BB + grow)) * DD + ocol] = f2b(v);
    } else {
      int t = t0 + (grow >> 2), b = grow & 3;
      int h = (ocol >> 6) & 15, d = ocol & 63;
      long dst = (((long)l * BB + b) * HH + h) * ((long)SS * DHH) + (long)t * DHH + d;
      if (ocol >= 2 * DD) vc[dst] = f2b(v); else kc[dst] = f2b(v);
    }
  }
}

// ---------------- big GEMM (BM=128): reg-staged, padded LDS, named-reg prefetch, split-K ----------------
template<int EPI>
__global__ __launch_bounds__(256) void gemm_k(const ushort* __restrict__ A, int lda,
                                              const ushort* __restrict__ BT,
                                              void* Cv, int ldc,
                                              const float* Add,
                                              int M, int N, int K, int gx,
                                              int l, int t0,
                                              ushort* kc, ushort* vc, ushort* qb,
                                              float* part, int KS)
{
  constexpr int BM  = 128;
  constexpr int MFR = 4;
  constexpr int NFR = 4;
  __shared__ ushort As[BM][72];
  __shared__ ushort Bs[128][72];
  int tid = threadIdx.x;
  int wv = tid >> 6, lane = tid & 63;
  int wm = wv >> 1, wn = wv & 1;

  int nwg = gridDim.x, orig = blockIdx.x;
  int wgid;
  if (nwg <= 1024){
    int qq = nwg >> 3, rr8 = nwg & 7, xcd = orig & 7;
    wgid = ((xcd < rr8) ? xcd * (qq + 1) : rr8 * (qq + 1) + (xcd - rr8) * qq) + (orig >> 3);
  } else {
    wgid = orig;
  }

  int gxy = gx * (N >> 7);
  int ksId = wgid / gxy;
  int rem  = wgid - ksId * gxy;
  int bx = rem % gx, by = rem / gx;
  int m0 = bx * BM, n0 = by * 128;
  int Kc = K / KS;
  int k_beg = ksId * Kc, k_end = k_beg + Kc;

  f32x4 acc[MFR][NFR];
  f32x4 zz = {0.f, 0.f, 0.f, 0.f};
#pragma unroll
  for (int m = 0; m < MFR; m++)
#pragma unroll
    for (int n = 0; n < NFR; n++) acc[m][n] = zz;

  int g4 = (lane >> 4) * 4;
  int rA = lane & 15;
  int arow = tid >> 3;
  int acol = (tid & 7) * 8;

  const ushort* Bp = BT + (long)(n0 + arow) * K + acol;
  long sB = 32 * (long)K;
  int gr0 = m0 + arow;       if (gr0 > M - 1) gr0 = M - 1;
  int gr1 = m0 + 32 + arow;  if (gr1 > M - 1) gr1 = M - 1;
  int gr2 = m0 + 64 + arow;  if (gr2 > M - 1) gr2 = M - 1;
  int gr3 = m0 + 96 + arow;  if (gr3 > M - 1) gr3 = M - 1;
  const ushort* Ap0 = A + (long)gr0 * lda + acol;
  const ushort* Ap1 = A + (long)gr1 * lda + acol;
  const ushort* Ap2 = A + (long)gr2 * lda + acol;
  const ushort* Ap3 = A + (long)gr3 * lda + acol;

  uint4 b0 = *(const uint4*)(Bp + k_beg);
  uint4 b1 = *(const uint4*)(Bp + sB + k_beg);
  uint4 b2 = *(const uint4*)(Bp + 2 * sB + k_beg);
  uint4 b3 = *(const uint4*)(Bp + 3 * sB + k_beg);
  uint4 a0 = *(const uint4*)(Ap0 + k_beg);
  uint4 a1 = *(const uint4*)(Ap1 + k_beg);
  uint4 a2 = *(const uint4*)(Ap2 + k_beg);
  uint4 a3 = *(const uint4*)(Ap3 + k_beg);

  for (int k0 = k_beg; k0 < k_end; k0 += 64){
    *(uint4*)&Bs[arow     ][acol] = b0;
    *(uint4*)&Bs[arow + 32][acol] = b1;
    *(uint4*)&Bs[arow + 64][acol] = b2;
    *(uint4*)&Bs[arow + 96][acol] = b3;
    *(uint4*)&As[arow     ][acol] = a0;
    *(uint4*)&As[arow + 32][acol] = a1;
    *(uint4*)&As[arow + 64][acol] = a2;
    *(uint4*)&As[arow + 96][acol] = a3;
    __syncthreads();
    int kn = k0 + 64;
    if (kn < k_end){
      b0 = *(const uint4*)(Bp + kn);
      b1 = *(const uint4*)(Bp + sB + kn);
      b2 = *(const uint4*)(Bp + 2 * sB + kn);
      b3 = *(const uint4*)(Bp + 3 * sB + kn);
      a0 = *(const uint4*)(Ap0 + kn);
      a1 = *(const uint4*)(Ap1 + kn);
      a2 = *(const uint4*)(Ap2 + kn);
      a3 = *(const uint4*)(Ap3 + kn);
    }
#pragma unroll
    for (int kk = 0; kk < 64; kk += 32){
      bf16x8 af[MFR], bfr[NFR];
#pragma unroll
      for (int m = 0; m < MFR; m++){
        int row = wm * 64 + m * 16 + rA;
        bf16x4v lo = *(const bf16x4v*)&As[row][kk + g4];
        bf16x4v hi = *(const bf16x4v*)&As[row][kk + 16 + g4];
        af[m] = __builtin_shufflevector(lo, hi, 0, 1, 2, 3, 4, 5, 6, 7);
      }
#pragma unroll
      for (int n = 0; n < NFR; n++){
        int row = wn * 64 + n * 16 + rA;
        bf16x4v lo = *(const bf16x4v*)&Bs[row][kk + g4];
        bf16x4v hi = *(const bf16x4v*)&Bs[row][kk + 16 + g4];
        bfr[n] = __builtin_shufflevector(lo, hi, 0, 1, 2, 3, 4, 5, 6, 7);
      }
#pragma unroll
      for (int m = 0; m < MFR; m++)
#pragma unroll
        for (int n = 0; n < NFR; n++)
          acc[m][n] = __builtin_amdgcn_mfma_f32_16x16x32_bf16(af[m], bfr[n], acc[m][n], 0, 0, 0);
    }
    __syncthreads();
  }

  int r4 = (lane >> 4) * 4;
#pragma unroll
  for (int m = 0; m < MFR; m++){
#pragma unroll
    for (int n = 0; n < NFR; n++){
      int orow = wm * 64 + m * 16 + r4;
      int ocol = n0 + wn * 64 + n * 16 + rA;
#pragma unroll
      for (int r = 0; r < 4; r++){
        int grow = m0 + orow + r;
        if (grow < M){
          if (KS > 1)
            part[(long)ksId * M * N + (long)grow * N + ocol] = acc[m][n][r];
          else
            epi_store<EPI>(acc[m][n][r], grow, ocol, Cv, ldc, Add, t0, l, kc, vc, qb);
        }
      }
    }
  }
}

// ---------------- split-K reduce (applies epilogue) ----------------
template<int EPI>
__global__ __launch_bounds__(256) void sred_k(const float* __restrict__ part, int KS, int M, int N,
                                              void* Cv, int ldc, const float* Add,
                                              int l, int t0, ushort* kc, ushort* vc, ushort* qb)
{
  long i = (long)blockIdx.x * 256 + threadIdx.x;
  long MN = (long)M * N;
  if (i >= MN) return;
  float v = 0.f;
  for (int s = 0; s < KS; s++) v += part[s * MN + i];
  int m = (int)(i / N), n = (int)(i - (long)m * N);
  epi_store<EPI>(v, m, n, Cv, ldc, Add, t0, l, kc, vc, qb);
}

// ---------------- decode GEMV (M=4): one output column per wave ----------------
template<int TYPE>
__global__ __launch_bounds__(256) void dec_gemv_k(const float* xf, const ushort* ab,
                                                  const float* g, const float* bt,
                                                  const ushort* WT, float* x,
                                                  ushort* qb, ushort* kc, ushort* vc, ushort* gb,
                                                  int l, int pos)
{
  constexpr int K   = (TYPE == 3) ? FFF : DD;
  constexpr int NCH = K / 1024;
  int tid = threadIdx.x, wid = tid >> 6, lane = tid & 63;
  int n = blockIdx.x * 4 + wid;

  float acc[4] = {0.f, 0.f, 0.f, 0.f};

#pragma unroll
  for (int ch = 0; ch < NCH; ch++){
    int ks = ch * 1024 + lane * 16;
    float a[4][16];
    if constexpr (TYPE == 0 || TYPE == 2){
#pragma unroll
      for (int r = 0; r < 4; r++){
        const float* rp = xf + (long)(pos * BB + r) * DD + ks;
#pragma unroll
        for (int q = 0; q < 4; q++){
          float4 v = *(const float4*)(rp + q * 4);
          a[r][q*4+0] = v.x; a[r][q*4+1] = v.y; a[r][q*4+2] = v.z; a[r][q*4+3] = v.w;
        }
      }
      float gj[16], bj[16];
#pragma unroll
      for (int q = 0; q < 4; q++){
        float4 gv = *(const float4*)(g  + ks + q * 4);
        float4 bv = *(const float4*)(bt + ks + q * 4);
        gj[q*4+0]=gv.x; gj[q*4+1]=gv.y; gj[q*4+2]=gv.z; gj[q*4+3]=gv.w;
        bj[q*4+0]=bv.x; bj[q*4+1]=bv.y; bj[q*4+2]=bv.z; bj[q*4+3]=bv.w;
      }
#pragma unroll
      for (int r = 0; r < 4; r++){
        float s1 = 0.f, s2 = 0.f;
#pragma unroll
        for (int j = 0; j < 16; j++){ s1 += a[r][j]; s2 += a[r][j] * a[r][j]; }
#pragma unroll
        for (int o = 32; o; o >>= 1){ s1 += __shfl_xor(s1, o); s2 += __shfl_xor(s2, o); }
        float mean = s1 * (1.0f / DD);
        float var  = s2 * (1.0f / DD) - mean * mean;
        float rstd = rsqrtf(var + 1e-5f);
#pragma unroll
        for (int j = 0; j < 16; j++)
          a[r][j] = b2f(f2b((a[r][j] - mean) * rstd * gj[j] + bj[j]));   // match bf16 hbuf path
      }
    } else {
      constexpr int AD = (TYPE == 3) ? FFF : DD;
#pragma unroll
      for (int r = 0; r < 4; r++){
        const ushort* rp = ab + (long)(pos * BB + r) * AD + ks;
        uint4 pa = *(const uint4*)rp;
        uint4 pb = *(const uint4*)(rp + 8);
        const unsigned int w[8] = {pa.x, pa.y, pa.z, pa.w, pb.x, pb.y, pb.z, pb.w};
#pragma unroll
        for (int q = 0; q < 8; q++){
          a[r][q*2]   = b2f((ushort)(w[q] & 0xffff));
          a[r][q*2+1] = b2f((ushort)(w[q] >> 16));
        }
      }
    }
    {
      const ushort* wp = WT + (long)n * K + ks;
      uint4 pa = *(const uint4*)wp;
      uint4 pb = *(const uint4*)(wp + 8);
      const unsigned int w[8] = {pa.x, pa.y, pa.z, pa.w, pb.x, pb.y, pb.z, pb.w};
      float wf[16];
#pragma unroll
      for (int q = 0; q < 8; q++){
        wf[q*2]   = b2f((ushort)(w[q] & 0xffff));
        wf[q*2+1] = b2f((ushort)(w[q] >> 16));
      }
#pragma unroll
      for (int r = 0; r < 4; r++){
        float s = 0.f;
#pragma unroll
        for (int j = 0; j < 16; j++) s += a[r][j] * wf[j];
        acc[r] += s;
      }
    }
  }

#pragma unroll
  for (int r = 0; r < 4; r++)
#pragma unroll
    for (int o = 32; o; o >>= 1) acc[r] += __shfl_xor(acc[r], o);

  if (lane < 4){
    int r = lane;
    long Rrow = (long)(pos * BB + r);
    float v = acc[r];
    if constexpr (TYPE == 0){
      if (n < DD){
        qb[Rrow * DD + n] = f2b(v);
      } else if (n < 2 * DD){
        int h = (n - DD) >> 6, d = n & 63;
        kc[(((long)l * BB + r) * HH + h) * ((long)SS * DHH) + (long)pos * DHH + d] = f2b(v);
      } else {
        int h = (n - 2 * DD) >> 6, d = n & 63;
        vc[(((long)l * BB + r) * HH + h) * ((long)SS * DHH) + (long)pos * DHH + d] = f2b(v);
      }
    } else if constexpr (TYPE == 2){
      float tt = 0.7978845608028654f * (v + 0.044715f * v * v * v);
      gb[Rrow * FFF + n] = f2b(0.5f * v * (1.0f + tanhf(tt)));
    } else {
      long idx = Rrow * DD + n;
      x[idx] = x[idx] + v;
    }
  }
}

// ---------------- decode final: lnf + hid write + advance ----------------
__global__ __launch_bounds__(256) void dec_final_k(const float* xf, const float* g, const float* bt,
                                                   const float* pe, ushort* hid, float* x,
                                                   float* oemb, int pos)
{
  int wid = threadIdx.x >> 6, lane = threadIdx.x & 63;
  long R = (long)(pos * BB + wid);
  const float* rp = xf + R * DD + lane * 16;
  float a[16];
#pragma unroll
  for (int q = 0; q < 4; q++){
    float4 v = *(const float4*)(rp + q * 4);
    a[q*4+0] = v.x; a[q*4+1] = v.y; a[q*4+2] = v.z; a[q*4+3] = v.w;
  }
  float s1 = 0.f, s2 = 0.f;
#pragma unroll
  for (int j = 0; j < 16; j++){ s1 += a[j]; s2 += a[j] * a[j]; }
#pragma unroll
  for (int o = 32; o; o >>= 1){ s1 += __shfl_xor(s1, o); s2 += __shfl_xor(s2, o); }
  float mean = s1 * (1.0f / DD);
  float var  = s2 * (1.0f / DD) - mean * mean;
  float rstd = rsqrtf(var + 1e-5f);
  int pn = pos + 1;
#pragma unroll
  for (int j = 0; j < 16; j++){
    int d = lane * 16 + j;
    ushort hb = f2b((a[j] - mean) * rstd * g[d] + bt[d]);
    hid[R * DD + d] = hb;
    float hv = b2f(hb);
    oemb[((long)wid * SS + pn) * DD + d] = hv;
    x[((long)(pn * BB + wid)) * DD + d] = hv + pe[(long)pn * DD + d];
  }
}

// ---------------- attention (token-major q/o, cached k/v) ----------------
__global__ __launch_bounds__(256) void attn_k(const ushort* __restrict__ qb, const ushort* __restrict__ kc,
                                              const ushort* __restrict__ vc, ushort* __restrict__ o,
                                              int l, int t0, int Tc)
{
  __shared__ float sc[4][512];
  __shared__ float qs[4][64];
  int tid = threadIdx.x, wv = tid >> 6, lane = tid & 63;
  int b = blockIdx.z, h = blockIdx.y;
  int qrow = blockIdx.x * 4 + wv;
  bool act = qrow < Tc;
  int tq = t0 + qrow;
  long kvoff = (((long)l * BB + b) * HH + h) * ((long)SS * DHH);
  const ushort* kb = kc + kvoff;
  const ushort* vb = vc + kvoff;
  if (act) qs[wv][lane] = b2f(qb[((long)(tq * BB + b)) * DD + h * DHH + lane]);
  __syncthreads();
  int nk = act ? (tq + 1) : 0;
  float m = -3.0e38f;
  for (int key = lane; key < nk; key += 64){
    const ushort* kp = kb + (long)key * DHH;
    float s = 0.f;
#pragma unroll
    for (int j = 0; j < 8; j++){
      uint4 kvv = *(const uint4*)(kp + j * 8);
      s += qs[wv][j*8+0] * b2f((ushort)(kvv.x & 0xffff));
      s += qs[wv][j*8+1] * b2f((ushort)(kvv.x >> 16));
      s += qs[wv][j*8+2] * b2f((ushort)(kvv.y & 0xffff));
      s += qs[wv][j*8+3] * b2f((ushort)(kvv.y >> 16));
      s += qs[wv][j*8+4] * b2f((ushort)(kvv.z & 0xffff));
      s += qs[wv][j*8+5] * b2f((ushort)(kvv.z >> 16));
      s += qs[wv][j*8+6] * b2f((ushort)(kvv.w & 0xffff));
      s += qs[wv][j*8+7] * b2f((ushort)(kvv.w >> 16));
    }
    s *= 0.125f;
    sc[wv][key] = s;
    m = fmaxf(m, s);
  }
#pragma unroll
  for (int off = 32; off; off >>= 1) m = fmaxf(m, __shfl_xor(m, off));
  float ssum = 0.f;
  for (int key = lane; key < nk; key += 64){
    float p = expf(sc[wv][key] - m);
    sc[wv][key] = p;
    ssum += p;
  }
#pragma unroll
  for (int off = 32; off; off >>= 1) ssum += __shfl_xor(ssum, off);
  __syncthreads();
  float accv = 0.f;
  int key = 0;
  for (; key + 3 < nk; key += 4){
    float p0 = sc[wv][key],     p1 = sc[wv][key + 1];
    float p2 = sc[wv][key + 2], p3 = sc[wv][key + 3];
    float v0 = b2f(vb[(long)key * DHH + lane]);
    float v1 = b2f(vb[(long)(key + 1) * DHH + lane]);
    float v2 = b2f(vb[(long)(key + 2) * DHH + lane]);
    float v3 = b2f(vb[(long)(key + 3) * DHH + lane]);
    accv += p0 * v0 + p1 * v1 + p2 * v2 + p3 * v3;
  }
  for (; key < nk; key++)
    accv += sc[wv][key] * b2f(vb[(long)key * DHH + lane]);
  if (act) o[((long)(tq * BB + b)) * DD + h * DHH + lane] = f2b(accv / ssum);
}

// ---------------- feedback (chunk-0 boundary only) ----------------
__global__ __launch_bounds__(256) void advance_k(const ushort* __restrict__ hid, const float* __restrict__ pe,
                                                 float* __restrict__ x, float* __restrict__ oemb, int pos)
{
  int d = blockIdx.x * 256 + threadIdx.x;
  int b = blockIdx.y;
  float hv = b2f(hid[((long)((pos - 1) * BB + b)) * DD + d]);
  oemb[((long)b * SS + pos) * DD + d] = hv;
  x[((long)(pos * BB + b)) * DD + d] = hv + pe[(long)pos * DD + d];
}

// ---------------- loss (float4 logits loads; head 0..2 + tail 31999 scalar) ----------------
__global__ __launch_bounds__(256) void loss_rows_k(const float* __restrict__ logits, const int* __restrict__ labels,
                                                   float* __restrict__ rowloss)
{
  int t = blockIdx.x, b = blockIdx.y, tid = threadIdx.x;
  const float* row = logits + ((long)b * SS + t) * VV;
  float m = -3.0e38f, s = 0.f;
  auto upd = [&](float v){
    if (v > m){ s = s * expf(m - v) + 1.f; m = v; }
    else s += expf(v - m);
  };
  if (tid < 3) upd(row[tid]);
  if (tid == 3) upd(row[VV - 1]);
  const float4* vrow = (const float4*)(row + 3);
  for (int i = tid; i < 7999; i += 256){
    float4 v = vrow[i];
    upd(v.x); upd(v.y); upd(v.z); upd(v.w);
  }
#pragma unroll
  for (int off = 32; off; off >>= 1){
    float om = __shfl_xor(m, off), os = __shfl_xor(s, off);
    float nm = fmaxf(m, om);
    s = s * expf(m - nm) + os * expf(om - nm);
    m = nm;
  }
  __shared__ float sm[4], ssb[4];
  if ((tid & 63) == 0){ sm[tid >> 6] = m; ssb[tid >> 6] = s; }
  __syncthreads();
  if (tid == 0){
    float M = fmaxf(fmaxf(sm[0], sm[1]), fmaxf(sm[2], sm[3]));
    float S = ssb[0] * expf(sm[0] - M) + ssb[1] * expf(sm[1] - M)
            + ssb[2] * expf(sm[2] - M) + ssb[3] * expf(sm[3] - M);
    int lab = labels[b * SS + t + 1];
    rowloss[b * (SS - 1) + t] = (M + logf(S)) - row[lab];
  }
}

__global__ __launch_bounds__(256) void loss_final_k(const float* __restrict__ rowloss, float* __restrict__ out)
{
  int tid = threadIdx.x;
  float s = 0.f;
  for (int i = tid; i < BB * (SS - 1); i += 256) s += rowloss[i];
#pragma unroll
  for (int o = 32; o; o >>= 1) s += __shfl_down(s, o);
  __shared__ float red[4];
  if ((tid & 63) == 0) red[tid >> 6] = s;
  __syncthreads();
  if (tid == 0) out[0] = (red[0] + red[1] + red[2] + red[3]) / (float)(BB * (SS - 1));
}

// ---------------- host ----------------
static inline int cdiv_i(int a, int b){ return (a + b - 1) / b; }

extern "C" void kernel_launch(void* const* d_in, const int* in_sizes, int n_in,
                              void* d_out, int out_size, void* d_ws, size_t ws_size,
                              hipStream_t stream)
{
  (void)in_sizes; (void)n_in; (void)out_size; (void)ws_size;
  const int*   ids    = (const int*)d_in[0];
  const int*   labels = (const int*)d_in[2];
  const float* emb    = (const float*)d_in[4];
  const float* pe     = (const float*)d_in[5];
  const float* Wqkv   = (const float*)d_in[6];
  const float* Wo     = (const float*)d_in[7];
  const float* W1     = (const float*)d_in[8];
  const float* W2     = (const float*)d_in[9];
  const float* ln1g   = (const float*)d_in[10];
  const float* ln1b   = (const float*)d_in[11];
  const float* ln2g   = (const float*)d_in[12];
  const float* ln2b   = (const float*)d_in[13];
  const float* lnfg   = (const float*)d_in[14];
  const float* lnfb   = (const float*)d_in[15];
  const float* lm     = (const float*)d_in[16];

  float* out_loss   = (float*)d_out;
  float* out_emb    = out_loss + 1;
  float* out_logits = out_emb + (size_t)BB * SS * DD;

  char* wsp = (char*)d_ws;
  size_t off = 0;
  auto alloc = [&](size_t bytes) -> void* {
    void* p = wsp + off; off += (bytes + 255) & ~(size_t)255; return p;
  };
  ushort* wqkvT = (ushort*)alloc((size_t)LL * 3 * DD * DD * 2);
  ushort* woT   = (ushort*)alloc((size_t)LL * DD * DD * 2);
  ushort* w1T   = (ushort*)alloc((size_t)LL * FFF * DD * 2);
  ushort* w2T   = (ushort*)alloc((size_t)LL * DD * FFF * 2);
  ushort* lmT   = (ushort*)alloc((size_t)VV * DD * 2);
  float*  x     = (float*)alloc((size_t)BB * SS * DD * 4);
  ushort* hbuf  = (ushort*)alloc((size_t)BB * SS * DD * 2);
  ushort* qbuf  = (ushort*)alloc((size_t)BB * SS * DD * 2);
  ushort* obuf  = (ushort*)alloc((size_t)BB * SS * DD * 2);
  ushort* gbuf  = (ushort*)alloc((size_t)BB * SS * FFF * 2);
  ushort* hid   = (ushort*)alloc((size_t)BB * SS * DD * 2);
  ushort* kcache= (ushort*)alloc((size_t)LL * BB * SS * DD * 2);
  ushort* vcache= (ushort*)alloc((size_t)LL * BB * SS * DD * 2);
  float*  part  = (float*)alloc((size_t)17 * 1024 * 1024);
  float*  rowls = (float*)alloc((size_t)BB * (SS - 1) * 4);

  convT_k<<<dim3(3 * DD / 64, DD / 64, LL), dim3(256), 0, stream>>>(Wqkv, wqkvT, DD, 3 * DD, (long)DD * 3 * DD, (long)3 * DD * DD);
  convT_k<<<dim3(DD / 64, DD / 64, LL),     dim3(256), 0, stream>>>(Wo,   woT,  DD, DD,     (long)DD * DD,     (long)DD * DD);
  convT_k<<<dim3(FFF / 64, DD / 64, LL),    dim3(256), 0, stream>>>(W1,   w1T,  DD, FFF,    (long)DD * FFF,    (long)FFF * DD);
  convT_k<<<dim3(DD / 64, FFF / 64, LL),    dim3(256), 0, stream>>>(W2,   w2T,  FFF, DD,    (long)FFF * DD,    (long)DD * FFF);
  convT_k<<<dim3(VV / 64, DD / 64, 1),      dim3(256), 0, stream>>>(lm,   lmT,  DD, VV,     0, 0);

  embed_k<<<dim3(SS, BB), dim3(256), 0, stream>>>(ids, emb, pe, x, out_emb);

  const int ct0[7] = {0, 64, 65, 66, 67, 68, 69};
  const int ct1[7] = {64, 65, 66, 67, 68, 69, 512};

  auto g128 = [&](int epi, const ushort* A, int lda, const ushort* BT, void* C, int ldc,
                  const float* Add, int M, int N, int K, int l, int t0, int KS){
    int gx = cdiv_i(M, 128);
    int nwg = gx * (N >> 7) * KS;
    if (epi == 1) gemm_k<1><<<nwg, 256, 0, stream>>>(A, lda, BT, C, ldc, Add, M, N, K, gx, l, t0, kcache, vcache, qbuf, part, KS);
    if (epi == 2) gemm_k<2><<<nwg, 256, 0, stream>>>(A, lda, BT, C, ldc, Add, M, N, K, gx, l, t0, kcache, vcache, qbuf, part, KS);
    if (epi == 3) gemm_k<3><<<nwg, 256, 0, stream>>>(A, lda, BT, C, ldc, Add, M, N, K, gx, l, t0, kcache, vcache, qbuf, part, KS);
    if (epi == 4) gemm_k<4><<<nwg, 256, 0, stream>>>(A, lda, BT, C, ldc, Add, M, N, K, gx, l, t0, kcache, vcache, qbuf, part, KS);
    if (KS > 1){
      int nred = cdiv_i(M * N, 256);
      if (epi == 1) sred_k<1><<<nred, 256, 0, stream>>>(part, KS, M, N, C, ldc, Add, l, t0, kcache, vcache, qbuf);
      if (epi == 2) sred_k<2><<<nred, 256, 0, stream>>>(part, KS, M, N, C, ldc, Add, l, t0, kcache, vcache, qbuf);
      if (epi == 4) sred_k<4><<<nred, 256, 0, stream>>>(part, KS, M, N, C, ldc, Add, l, t0, kcache, vcache, qbuf);
    }
  };

  for (int c = 0; c < 7; c++){
    int t0 = ct0[c];
    int Tc = ct1[c] - t0;
    int M  = Tc * BB;
    long roff = (long)t0 * BB;

    if (Tc == 1){
      int pos = t0;
      for (int l = 0; l < LL; l++){
        dec_gemv_k<0><<<dim3(3 * DD / 4), dim3(256), 0, stream>>>(x, nullptr, ln1g + l * DD, ln1b + l * DD,
            wqkvT + (long)l * 3 * DD * DD, nullptr, qbuf, kcache, vcache, nullptr, l, pos);
        attn_k<<<dim3(1, HH, BB), dim3(64), 0, stream>>>(qbuf, kcache, vcache, obuf, l, t0, Tc);
        dec_gemv_k<1><<<dim3(DD / 4), dim3(256), 0, stream>>>(nullptr, obuf, nullptr, nullptr,
            woT + (long)l * DD * DD, x, nullptr, nullptr, nullptr, nullptr, l, pos);
        dec_gemv_k<2><<<dim3(FFF / 4), dim3(256), 0, stream>>>(x, nullptr, ln2g + l * DD, ln2b + l * DD,
            w1T + (long)l * FFF * DD, nullptr, nullptr, nullptr, nullptr, gbuf, l, pos);
        dec_gemv_k<3><<<dim3(DD / 4), dim3(256), 0, stream>>>(nullptr, gbuf, nullptr, nullptr,
            w2T + (long)l * DD * FFF, x, nullptr, nullptr, nullptr, nullptr, l, pos);
      }
      dec_final_k<<<dim3(1), dim3(256), 0, stream>>>(x, lnfg, lnfb, pe, hid, x, out_emb, pos);
    } else {
      bool small = (M <= 256);
      int ksQKV = small ? 4 : 1;
      int ksWO  = small ? 8 : 2;
      int ksW1  = small ? 4 : 1;
      int ksW2  = small ? 8 : 2;
      for (int l = 0; l < LL; l++){
        ln_k<<<dim3(M), dim3(256), 0, stream>>>(x, ln1g + l * DD, ln1b + l * DD, hbuf, roff);
        g128(4, hbuf + roff * DD, DD, wqkvT + (long)l * 3 * DD * DD, nullptr, 0, nullptr, M, 3 * DD, DD, l, t0, ksQKV);
        attn_k<<<dim3(cdiv_i(Tc, 4), HH, BB), dim3(256), 0, stream>>>(qbuf, kcache, vcache, obuf, l, t0, Tc);
        g128(1, obuf + roff * DD, DD, woT + (long)l * DD * DD, x + roff * DD, DD, x + roff * DD, M, DD, DD, l, t0, ksWO);
        ln_k<<<dim3(M), dim3(256), 0, stream>>>(x, ln2g + l * DD, ln2b + l * DD, hbuf, roff);
        g128(2, hbuf + roff * DD, DD, w1T + (long)l * FFF * DD, gbuf + roff * FFF, FFF, nullptr, M, FFF, DD, l, t0, ksW1);
        g128(1, gbuf + roff * FFF, FFF, w2T + (long)l * DD * FFF, x + roff * DD, DD, x + roff * DD, M, DD, FFF, l, t0, ksW2);
      }
      ln_k<<<dim3(M), dim3(256), 0, stream>>>(x, lnfg, lnfb, hid, roff);
      if (c == 0)
        advance_k<<<dim3(DD / 256, BB), dim3(256), 0, stream>>>(hid, pe, x, out_emb, 64);
    }
  }

  // single deferred lm_head over all positions
  g128(3, hid, DD, lmT, out_logits, 0, nullptr, BB * SS, VV, DD, 0, 0, 1);

  loss_rows_k<<<dim3(SS - 1, BB), dim3(256), 0, stream>>>(out_logits, labels, rowls);
  loss_final_k<<<dim3(1), dim3(256), 0, stream>>>(rowls, out_loss);
}